// Round 1
// baseline (823.448 us; speedup 1.0000x reference)
//
#include <hip/hip_runtime.h>

// RecursiveLSTM: B=1024 independent sequences, T=96, H=50, num_pred=12.
// One block per batch element; 1152 serial LSTM steps inside the kernel.
// Thread j<200 owns gate j (W_hh row in registers); h broadcast via LDS.

#define HSZ   50
#define G4    200      // 4*H gates
#define TLEN  96
#define MAXP  16       // >= num_pred

__device__ __forceinline__ float sigmoid_(float x) {
    // safe at +/-inf: exp(-x)->inf gives 0, ->0 gives 1
    return 1.0f / (1.0f + __expf(-x));
}
__device__ __forceinline__ float tanh_(float x) {
    // 1 - 2/(exp(2x)+1): no inf/inf NaN at large |x|
    return 1.0f - 2.0f / (__expf(2.0f * x) + 1.0f);
}

__global__ __launch_bounds__(256, 4)
void rec_lstm_kernel(const float* __restrict__ x,
                     const float* __restrict__ W_ih,
                     const float* __restrict__ W_hh,
                     const float* __restrict__ b_ih,
                     const float* __restrict__ b_hh,
                     const float* __restrict__ W_fc,
                     const float* __restrict__ b_fc,
                     const int*   __restrict__ num_pred,
                     float*       __restrict__ out)
{
    const int b   = blockIdx.x;
    const int tid = threadIdx.x;

    __shared__ float x_lds[TLEN];
    __shared__ float preds[MAXP];
    __shared__ __align__(16) float h_lds[52];   // padded to 13 float4
    __shared__ float gates[G4];

    // ---- one-time preload ----
    float w[52];          // W_hh row for gate tid (padded with zeros)
    float wih = 0.f, bsum = 0.f, wfc = 0.f;
    if (tid < G4) {
        wih  = W_ih[tid];
        bsum = b_ih[tid] + b_hh[tid];
        #pragma unroll
        for (int k = 0; k < HSZ; ++k) w[k] = W_hh[tid * HSZ + k];
        w[50] = 0.f; w[51] = 0.f;
    }
    if (tid < HSZ)  wfc = W_fc[tid];
    if (tid < TLEN) x_lds[tid] = x[b * TLEN + tid];
    if (tid == 0) { h_lds[50] = 0.f; h_lds[51] = 0.f; }
    const float bfc = b_fc[0];
    const int   NP  = num_pred[0];

    float c = 0.f;   // cell state, valid in threads < 50

    for (int p = 0; p < NP; ++p) {
        if (tid < HSZ) { c = 0.f; h_lds[tid] = 0.f; }
        __syncthreads();

        for (int t = 0; t < TLEN; ++t) {
            const int idx = p + t;                       // sliding window
            const float xv = (idx < TLEN) ? x_lds[idx] : preds[idx - TLEN];

            if (tid < G4) {
                float acc = fmaf(wih, xv, bsum);
                const float4* h4 = (const float4*)h_lds;  // broadcast reads
                #pragma unroll
                for (int kk = 0; kk < 13; ++kk) {
                    float4 hv = h4[kk];
                    acc = fmaf(w[4*kk+0], hv.x, acc);
                    acc = fmaf(w[4*kk+1], hv.y, acc);
                    acc = fmaf(w[4*kk+2], hv.z, acc);
                    acc = fmaf(w[4*kk+3], hv.w, acc);
                }
                // gate order i,f,g,o: tanh only for g (100..149)
                const float a = (tid < 100 || tid >= 150) ? sigmoid_(acc)
                                                          : tanh_(acc);
                gates[tid] = a;
            }
            __syncthreads();

            if (tid < HSZ) {
                const float gi = gates[tid];
                const float gf = gates[tid + 50];
                const float gg = gates[tid + 100];
                const float go = gates[tid + 150];
                c = fmaf(gf, c, gi * gg);
                h_lds[tid] = go * tanh_(c);
            }
            __syncthreads();
        }

        // ---- FC head: pred = h . W_fc + b_fc (wave-0 reduction) ----
        float v = (tid < HSZ) ? h_lds[tid] * wfc : 0.f;
        if (tid < 64) {
            #pragma unroll
            for (int off = 32; off >= 1; off >>= 1)
                v += __shfl_down(v, off, 64);
            if (tid == 0) {
                const float pr = v + bfc;
                preds[p] = pr;
                out[b * NP + p] = pr;
            }
        }
        __syncthreads();   // preds visible before next pass reads it
    }
}

extern "C" void kernel_launch(void* const* d_in, const int* in_sizes, int n_in,
                              void* d_out, int out_size, void* d_ws, size_t ws_size,
                              hipStream_t stream)
{
    const float* x    = (const float*)d_in[0];
    const float* W_ih = (const float*)d_in[1];
    const float* W_hh = (const float*)d_in[2];
    const float* b_ih = (const float*)d_in[3];
    const float* b_hh = (const float*)d_in[4];
    const float* W_fc = (const float*)d_in[5];
    const float* b_fc = (const float*)d_in[6];
    const int*   np   = (const int*)d_in[7];
    float* out = (float*)d_out;

    const int B = in_sizes[0] / TLEN;   // 1024
    rec_lstm_kernel<<<B, 256, 0, stream>>>(x, W_ih, W_hh, b_ih, b_hh,
                                           W_fc, b_fc, np, out);
}